// Round 5
// baseline (611.014 us; speedup 1.0000x reference)
//
#include <hip/hip_runtime.h>
#include <hip/hip_bf16.h>

typedef unsigned short u16;
typedef unsigned int   u32;
typedef __attribute__((ext_vector_type(8))) short  s16x8;
typedef __attribute__((ext_vector_type(4))) float  f32x4;
typedef __attribute__((ext_vector_type(4))) unsigned short u16x4;

#define MT    8192   // B*S tokens
#define DE    2048   // embed dim
#define NEXP  64     // experts
#define ERDIM 4096   // experts * rank

// round-to-nearest-even f32 -> bf16
__device__ __forceinline__ u16 to_bf16(float f) {
  u32 u = __builtin_bit_cast(u32, f);
  u32 r = u + 0x7fffu + ((u >> 16) & 1u);
  return (u16)(r >> 16);
}

__global__ void cvt_f32_bf16(const float* __restrict__ in, u16* __restrict__ out, int n) {
  const int stride = gridDim.x * blockDim.x;
  for (int i = blockIdx.x * blockDim.x + threadIdx.x; i * 4 < n; i += stride) {
    const float4 v = *reinterpret_cast<const float4*>(in + (size_t)i * 4);
    u16x4 o;
    o.x = to_bf16(v.x); o.y = to_bf16(v.y); o.z = to_bf16(v.z); o.w = to_bf16(v.w);
    *reinterpret_cast<u16x4*>(out + (size_t)i * 4) = o;
  }
}

#define GLDS(gp, lp) __builtin_amdgcn_global_load_lds(                        \
    (const __attribute__((address_space(1))) void*)(gp),                      \
    (__attribute__((address_space(3))) void*)(lp), 16, 0, 0)

#define BAR() do { asm volatile("" ::: "memory");                             \
                   __builtin_amdgcn_s_barrier();                              \
                   asm volatile("" ::: "memory"); } while (0)

// C = A[M,K] * B[N,K]^T (bf16, row-major). 256x256 tile, BK=32, 8 waves (2Mx4N),
// 16x16x32 MFMA (proven conflict-free LDS read pattern). 4-slot LDS ring,
// prefetch distance 3, counted vmcnt (never 0 mid-loop).
// Per-tile order: [12 frag ds_reads] [GLDS t+3] [vmcnt(8)] [barrier] [16 MFMA]
// -> ds_read latency drains during vmcnt+barrier wait; post-barrier is pure MFMA.
// Safety: reads(t) follow barrier(t-1) whose vmcnt guaranteed tile t landed;
// GLDS(t+3) (issued post-barrier(t-1)) targets slot (t-1)&3 whose readers all
// completed before barrier(t-1).
// FUSE=1: C_bf16[m,n] = bf16( silu(acc) * mask[m, n>>6] );  FUSE=0: C_f32 = acc
template<int FUSE, int K>
__global__ __launch_bounds__(512, 2) void gemm_bt(
    const u16* __restrict__ A, const u16* __restrict__ Bm,
    const float* __restrict__ mask, void* __restrict__ Cout,
    const int M, const int N)
{
  constexpr int BM = 256, BN = 256, BK = 32;
  constexpr int NT = K / BK;
  __shared__ __align__(16) u16 lds[65536];   // 4 slots x (A 8K elem + B 8K elem)

  const int nbn = N / BN;
  const int nwg = (int)gridDim.x;
  const int cpx = nwg >> 3;                      // nwg % 8 == 0 for all our grids
  const int bid = (int)blockIdx.x;
  const int swz = (bid & 7) * cpx + (bid >> 3);  // bijective XCD swizzle
  const int bm = (swz / nbn) * BM;
  const int bn = (swz % nbn) * BN;

  const int tid  = (int)threadIdx.x;
  const int lane = tid & 63;
  const int w    = tid >> 6;       // wave 0..7
  const int wr   = w >> 2;         // 0..1: M row-group (128 rows)
  const int wc   = w & 3;          // 0..3: N col-group (64 cols)

  const int fr = lane & 15;                          // fragment row
  const int cp = (lane >> 4) ^ ((lane >> 1) & 3);    // swizzled granule col (read)

  // staging: wave w owns chunks {2w, 2w+1} (16 rows x 64B each) of both A and B.
  // linear LDS dest (global_load_lds) + inverse-swizzled per-lane global source.
  const int lr = lane >> 2;                          // row within chunk
  const int cl = (lane & 3) ^ ((lane >> 3) & 3);     // logical granule col (source)
  const int c0 = 2 * w, c1 = 2 * w + 1;
  const u16* aS0 = A  + (size_t)(bm + c0 * 16 + lr) * K + cl * 8;
  const u16* aS1 = A  + (size_t)(bm + c1 * 16 + lr) * K + cl * 8;
  const u16* bS0 = Bm + (size_t)(bn + c0 * 16 + lr) * K + cl * 8;
  const u16* bS1 = Bm + (size_t)(bn + c1 * 16 + lr) * K + cl * 8;

  f32x4 acc[8][4] = {};

  // ---- prologue: stage tiles 0,1,2 (issue order = consumption order) ----
#pragma unroll
  for (int t = 0; t < 3; ++t) {
    u16* dst = lds + t * 16384;
    GLDS(aS0 + t * BK, dst +        c0 * 512);
    GLDS(aS1 + t * BK, dst +        c1 * 512);
    GLDS(bS0 + t * BK, dst + 8192 + c0 * 512);
    GLDS(bS1 + t * BK, dst + 8192 + c1 * 512);
  }
  asm volatile("s_waitcnt vmcnt(8)" ::: "memory");   // tile 0 landed; 1,2 in flight
  BAR();

  // ---- main loop: one barrier per K-tile ----
#pragma unroll 4
  for (int t = 0; t < NT; ++t) {
    const u16* sA = lds + (t & 3) * 16384;
    const u16* sB = lds + (t & 3) * 16384 + 8192;

    // [1] all 12 fragment reads for tile t (proven conflict-free pattern)
    s16x8 afr[8], bfr[4];
#pragma unroll
    for (int m = 0; m < 8; ++m)
      afr[m] = *reinterpret_cast<const s16x8*>(
          &sA[(wr * 128 + m * 16 + fr) * 32 + cp * 8]);
#pragma unroll
    for (int n = 0; n < 4; ++n)
      bfr[n] = *reinterpret_cast<const s16x8*>(
          &sB[(wc * 64 + n * 16 + fr) * 32 + cp * 8]);

    // [2] stage tile t+3 into slot (t-1)&3
    if (t + 3 < NT) {
      u16* dst = lds + ((t + 3) & 3) * 16384;
      const size_t koff = (size_t)(t + 3) * BK;
      GLDS(aS0 + koff, dst +        c0 * 512);
      GLDS(aS1 + koff, dst +        c1 * 512);
      GLDS(bS0 + koff, dst + 8192 + c0 * 512);
      GLDS(bS1 + koff, dst + 8192 + c1 * 512);
    }

    // [3] counted vmcnt: tile t+1 landed (ds_read latency drains during this)
    if (t + 3 < NT)      asm volatile("s_waitcnt vmcnt(8)" ::: "memory");
    else if (t + 2 < NT) asm volatile("s_waitcnt vmcnt(4)" ::: "memory");
    else if (t + 1 < NT) asm volatile("s_waitcnt vmcnt(0)" ::: "memory");

    // [4] barrier: cross-wave landing guarantee + slot-reuse fence
    if (t + 1 < NT) BAR();

    // [5] pure-MFMA phase
    __builtin_amdgcn_s_setprio(1);
#pragma unroll
    for (int m = 0; m < 8; ++m)
#pragma unroll
      for (int n = 0; n < 4; ++n)
        acc[m][n] = __builtin_amdgcn_mfma_f32_16x16x32_bf16(
            afr[m], bfr[n], acc[m][n], 0, 0, 0);
    __builtin_amdgcn_s_setprio(0);
  }

  // ---- epilogue: C/D layout col=lane&15, row=(lane>>4)*4 + j ----
  const int rgrp = (lane >> 4) * 4;
  if (FUSE) {
    u16* H = (u16*)Cout;
    const int ew = (bn + wc * 64) >> 6;  // wave's 64-col span = exactly one expert
#pragma unroll
    for (int m = 0; m < 8; ++m) {
#pragma unroll
      for (int j = 0; j < 4; ++j) {
        const int grow = bm + wr * 128 + m * 16 + rgrp + j;
        const float mv = mask[(size_t)grow * NEXP + ew];
#pragma unroll
        for (int n = 0; n < 4; ++n) {
          const int gcol = bn + wc * 64 + n * 16 + fr;
          float v = acc[m][n][j];
          v = v / (1.0f + __expf(-v));   // silu
          H[(size_t)grow * N + gcol] = to_bf16(v * mv);
        }
      }
    }
  } else {
    float* O = (float*)Cout;
#pragma unroll
    for (int m = 0; m < 8; ++m) {
#pragma unroll
      for (int j = 0; j < 4; ++j) {
        const int grow = bm + wr * 128 + m * 16 + rgrp + j;
#pragma unroll
        for (int n = 0; n < 4; ++n) {
          const int gcol = bn + wc * 64 + n * 16 + fr;
          O[(size_t)grow * N + gcol] = acc[m][n][j];
        }
      }
    }
  }
}

extern "C" void kernel_launch(void* const* d_in, const int* in_sizes, int n_in,
                              void* d_out, int out_size, void* d_ws, size_t ws_size,
                              hipStream_t stream) {
  const float* x     = (const float*)d_in[0];
  const float* emask = (const float*)d_in[1];
  const float* w_up  = (const float*)d_in[2];
  const float* w_dn  = (const float*)d_in[3];
  float* out = (float*)d_out;

  // workspace (bf16): x[8192,2048] | w_up[4096,2048] | w_dn[2048,4096] | H[8192,4096]
  const size_t need = ((size_t)MT * DE + (size_t)ERDIM * DE + (size_t)DE * ERDIM +
                       (size_t)MT * ERDIM) * sizeof(u16);
  if (ws_size < need) return;

  u16* xb  = (u16*)d_ws;
  u16* wub = xb  + (size_t)MT * DE;
  u16* wdb = wub + (size_t)ERDIM * DE;
  u16* hb  = wdb + (size_t)DE * ERDIM;

  hipLaunchKernelGGL(cvt_f32_bf16, dim3(2048), dim3(256), 0, stream, x,    xb,  MT * DE);
  hipLaunchKernelGGL(cvt_f32_bf16, dim3(1024), dim3(256), 0, stream, w_up, wub, ERDIM * DE);
  hipLaunchKernelGGL(cvt_f32_bf16, dim3(1024), dim3(256), 0, stream, w_dn, wdb, DE * ERDIM);

  // GEMM1: H = silu(X @ Wup^T) * mask   [M=8192, N=4096, K=2048] -> 512 blocks
  hipLaunchKernelGGL((gemm_bt<1, DE>), dim3((MT / 256) * (ERDIM / 256)), dim3(512), 0, stream,
                     xb, wub, emask, (void*)hb, MT, ERDIM);
  // GEMM2: out = H @ Wdown^T             [M=8192, N=2048, K=4096] -> 256 blocks
  hipLaunchKernelGGL((gemm_bt<0, ERDIM>), dim3((MT / 256) * (DE / 256)), dim3(512), 0, stream,
                     hb, wdb, nullptr, (void*)out, MT, DE);
}

// Round 6
// 291.743 us; speedup vs baseline: 2.0944x; 2.0944x over previous
//
#include <hip/hip_runtime.h>
#include <hip/hip_bf16.h>

typedef unsigned short u16;
typedef unsigned int   u32;
typedef __attribute__((ext_vector_type(8))) short  s16x8;
typedef __attribute__((ext_vector_type(4))) float  f32x4;
typedef __attribute__((ext_vector_type(4))) unsigned short u16x4;

#define MT    8192   // B*S tokens
#define DE    2048   // embed dim
#define NEXP  64     // experts
#define ERDIM 4096   // experts * rank

// round-to-nearest-even f32 -> bf16
__device__ __forceinline__ u16 to_bf16(float f) {
  u32 u = __builtin_bit_cast(u32, f);
  u32 r = u + 0x7fffu + ((u >> 16) & 1u);
  return (u16)(r >> 16);
}

__global__ void cvt_f32_bf16(const float* __restrict__ in, u16* __restrict__ out, int n) {
  const int stride = gridDim.x * blockDim.x;
  for (int i = blockIdx.x * blockDim.x + threadIdx.x; i * 4 < n; i += stride) {
    const float4 v = *reinterpret_cast<const float4*>(in + (size_t)i * 4);
    u16x4 o;
    o.x = to_bf16(v.x); o.y = to_bf16(v.y); o.z = to_bf16(v.z); o.w = to_bf16(v.w);
    *reinterpret_cast<u16x4*>(out + (size_t)i * 4) = o;
  }
}

#define GLDS(gp, lp) __builtin_amdgcn_global_load_lds(                        \
    (const __attribute__((address_space(1))) void*)(gp),                      \
    (__attribute__((address_space(3))) void*)(lp), 16, 0, 0)

#define BAR() do { asm volatile("" ::: "memory");                             \
                   __builtin_amdgcn_s_barrier();                              \
                   asm volatile("" ::: "memory"); } while (0)

// C = A[M,K] * B[N,K]^T (bf16, row-major). 256x256 tile, BK=32, 8 waves (2Mx4N),
// 16x16x32 MFMA (proven conflict-free pattern). 4-slot ring, prefetch dist 3,
// counted vmcnt (never 0 mid-loop).
// Each K-tile = TWO m201-style phase sandwiches:
//   P1: [8 ds_read: A m0-3 + B n0-3] [GLDS A(t+3)] BAR | 16 MFMA | BAR
//   P2: [4 ds_read: A m4-7 (B live)] [GLDS B(t+3)] [vmcnt(8)] BAR | 16 MFMA
// Cross-fence liveness <= 8 frags (32 VGPR) -> no spill (R5's failure mode);
// ds_read latency drains under the barrier rendezvous; MFMA phases pure.
// Slot safety: GLDS(t+3) targets slot (t-1)&3, whose readers finished before
// the tile-(t-1) end barrier, which precedes these GLDS in program order.
// FUSE=1: C_bf16[m,n] = bf16( silu(acc) * mask[m, n>>6] );  FUSE=0: C_f32 = acc
template<int FUSE, int K>
__global__ __launch_bounds__(512, 2) void gemm_bt(
    const u16* __restrict__ A, const u16* __restrict__ Bm,
    const float* __restrict__ mask, void* __restrict__ Cout,
    const int M, const int N)
{
  constexpr int BM = 256, BN = 256, BK = 32;
  constexpr int NT = K / BK;
  __shared__ __align__(16) u16 lds[65536];   // 4 slots x (A 8K elem + B 8K elem)

  const int nbn = N / BN;
  const int nwg = (int)gridDim.x;
  const int cpx = nwg >> 3;                      // nwg % 8 == 0 for all our grids
  const int bid = (int)blockIdx.x;
  const int swz = (bid & 7) * cpx + (bid >> 3);  // bijective XCD swizzle
  const int bm = (swz / nbn) * BM;
  const int bn = (swz % nbn) * BN;

  const int tid  = (int)threadIdx.x;
  const int lane = tid & 63;
  const int w    = tid >> 6;       // wave 0..7
  const int wr   = w >> 2;         // 0..1: M row-group (128 rows)
  const int wc   = w & 3;          // 0..3: N col-group (64 cols)

  const int fr = lane & 15;                          // fragment row
  const int cp = (lane >> 4) ^ ((lane >> 1) & 3);    // swizzled granule col (read)

  // staging: wave w owns chunks {2w, 2w+1} (16 rows x 64B each) of both A and B.
  // linear LDS dest (global_load_lds) + inverse-swizzled per-lane global source.
  const int lr = lane >> 2;                          // row within chunk
  const int cl = (lane & 3) ^ ((lane >> 3) & 3);     // logical granule col (source)
  const int c0 = 2 * w, c1 = 2 * w + 1;
  const u16* aS0 = A  + (size_t)(bm + c0 * 16 + lr) * K + cl * 8;
  const u16* aS1 = A  + (size_t)(bm + c1 * 16 + lr) * K + cl * 8;
  const u16* bS0 = Bm + (size_t)(bn + c0 * 16 + lr) * K + cl * 8;
  const u16* bS1 = Bm + (size_t)(bn + c1 * 16 + lr) * K + cl * 8;

  f32x4 acc[8][4] = {};

  // ---- prologue: stage tiles 0,1,2 (issue order = consumption order) ----
#pragma unroll
  for (int t = 0; t < 3; ++t) {
    u16* dst = lds + t * 16384;
    GLDS(aS0 + t * BK, dst +        c0 * 512);
    GLDS(aS1 + t * BK, dst +        c1 * 512);
    GLDS(bS0 + t * BK, dst + 8192 + c0 * 512);
    GLDS(bS1 + t * BK, dst + 8192 + c1 * 512);
  }
  asm volatile("s_waitcnt vmcnt(8)" ::: "memory");   // tile 0 landed; 1,2 in flight
  BAR();

  // ---- main loop: 2 phase-sandwiches per K-tile ----
#pragma unroll 4
  for (int t = 0; t < NT; ++t) {
    const u16* sA = lds + (t & 3) * 16384;
    const u16* sB = lds + (t & 3) * 16384 + 8192;
    u16* dst = lds + ((t + 3) & 3) * 16384;
    const bool st = (t + 3 < NT);
    const size_t koff = (size_t)(t + 3) * BK;

    // ======== phase 1: A m0-3 + B, stage A(t+3), BAR, 16 MFMA, BAR ========
    s16x8 a0[4], bfr[4];
#pragma unroll
    for (int m = 0; m < 4; ++m)
      a0[m] = *reinterpret_cast<const s16x8*>(
          &sA[(wr * 128 + m * 16 + fr) * 32 + cp * 8]);
#pragma unroll
    for (int n = 0; n < 4; ++n)
      bfr[n] = *reinterpret_cast<const s16x8*>(
          &sB[(wc * 64 + n * 16 + fr) * 32 + cp * 8]);
    if (st) {
      GLDS(aS0 + koff, dst +        c0 * 512);
      GLDS(aS1 + koff, dst +        c1 * 512);
    }
    BAR();
    __builtin_amdgcn_sched_barrier(0);
    __builtin_amdgcn_s_setprio(1);
#pragma unroll
    for (int m = 0; m < 4; ++m)
#pragma unroll
      for (int n = 0; n < 4; ++n)
        acc[m][n] = __builtin_amdgcn_mfma_f32_16x16x32_bf16(
            a0[m], bfr[n], acc[m][n], 0, 0, 0);
    __builtin_amdgcn_s_setprio(0);
    BAR();

    // ======== phase 2: A m4-7 (B live), stage B(t+3), vmcnt, BAR, 16 MFMA ====
    s16x8 a1[4];
#pragma unroll
    for (int m = 0; m < 4; ++m)
      a1[m] = *reinterpret_cast<const s16x8*>(
          &sA[(wr * 128 + (4 + m) * 16 + fr) * 32 + cp * 8]);
    if (st) {
      GLDS(bS0 + koff, dst + 8192 + c0 * 512);
      GLDS(bS1 + koff, dst + 8192 + c1 * 512);
    }
    // counted tile-boundary drain: tile t+1 landed before its reads next iter
    if (t + 3 < NT)      asm volatile("s_waitcnt vmcnt(8)" ::: "memory");
    else if (t + 2 < NT) asm volatile("s_waitcnt vmcnt(4)" ::: "memory");
    else if (t + 1 < NT) asm volatile("s_waitcnt vmcnt(0)" ::: "memory");
    BAR();
    __builtin_amdgcn_sched_barrier(0);
    __builtin_amdgcn_s_setprio(1);
#pragma unroll
    for (int m = 0; m < 4; ++m)
#pragma unroll
      for (int n = 0; n < 4; ++n)
        acc[4 + m][n] = __builtin_amdgcn_mfma_f32_16x16x32_bf16(
            a1[m], bfr[n], acc[4 + m][n], 0, 0, 0);
    __builtin_amdgcn_s_setprio(0);
    if (t + 1 < NT) BAR();
  }

  // ---- epilogue: C/D layout col=lane&15, row=(lane>>4)*4 + j ----
  const int rgrp = (lane >> 4) * 4;
  if (FUSE) {
    u16* H = (u16*)Cout;
    const int ew = (bn + wc * 64) >> 6;  // wave's 64-col span = exactly one expert
#pragma unroll
    for (int m = 0; m < 8; ++m) {
#pragma unroll
      for (int j = 0; j < 4; ++j) {
        const int grow = bm + wr * 128 + m * 16 + rgrp + j;
        const float mv = mask[(size_t)grow * NEXP + ew];
#pragma unroll
        for (int n = 0; n < 4; ++n) {
          const int gcol = bn + wc * 64 + n * 16 + fr;
          float v = acc[m][n][j];
          v = v / (1.0f + __expf(-v));   // silu
          H[(size_t)grow * N + gcol] = to_bf16(v * mv);
        }
      }
    }
  } else {
    float* O = (float*)Cout;
#pragma unroll
    for (int m = 0; m < 8; ++m) {
#pragma unroll
      for (int j = 0; j < 4; ++j) {
        const int grow = bm + wr * 128 + m * 16 + rgrp + j;
#pragma unroll
        for (int n = 0; n < 4; ++n) {
          const int gcol = bn + wc * 64 + n * 16 + fr;
          O[(size_t)grow * N + gcol] = acc[m][n][j];
        }
      }
    }
  }
}

extern "C" void kernel_launch(void* const* d_in, const int* in_sizes, int n_in,
                              void* d_out, int out_size, void* d_ws, size_t ws_size,
                              hipStream_t stream) {
  const float* x     = (const float*)d_in[0];
  const float* emask = (const float*)d_in[1];
  const float* w_up  = (const float*)d_in[2];
  const float* w_dn  = (const float*)d_in[3];
  float* out = (float*)d_out;

  // workspace (bf16): x[8192,2048] | w_up[4096,2048] | w_dn[2048,4096] | H[8192,4096]
  const size_t need = ((size_t)MT * DE + (size_t)ERDIM * DE + (size_t)DE * ERDIM +
                       (size_t)MT * ERDIM) * sizeof(u16);
  if (ws_size < need) return;

  u16* xb  = (u16*)d_ws;
  u16* wub = xb  + (size_t)MT * DE;
  u16* wdb = wub + (size_t)ERDIM * DE;
  u16* hb  = wdb + (size_t)DE * ERDIM;

  hipLaunchKernelGGL(cvt_f32_bf16, dim3(2048), dim3(256), 0, stream, x,    xb,  MT * DE);
  hipLaunchKernelGGL(cvt_f32_bf16, dim3(1024), dim3(256), 0, stream, w_up, wub, ERDIM * DE);
  hipLaunchKernelGGL(cvt_f32_bf16, dim3(1024), dim3(256), 0, stream, w_dn, wdb, DE * ERDIM);

  // GEMM1: H = silu(X @ Wup^T) * mask   [M=8192, N=4096, K=2048] -> 512 blocks
  hipLaunchKernelGGL((gemm_bt<1, DE>), dim3((MT / 256) * (ERDIM / 256)), dim3(512), 0, stream,
                     xb, wub, emask, (void*)hb, MT, ERDIM);
  // GEMM2: out = H @ Wdown^T             [M=8192, N=2048, K=4096] -> 256 blocks
  hipLaunchKernelGGL((gemm_bt<0, ERDIM>), dim3((MT / 256) * (DE / 256)), dim3(512), 0, stream,
                     hb, wdb, nullptr, (void*)out, MT, DE);
}